// Round 1
// baseline (613.439 us; speedup 1.0000x reference)
//
#include <hip/hip_runtime.h>
#include <hip/hip_bf16.h>

#define NB 64
#define NL 512
#define ND 128
#define NK 256   // concat(Q,UQ) contraction dim

typedef unsigned short ush;

__device__ __forceinline__ float bf2f(ush u) {
    union { unsigned int i; float f; } v; v.i = ((unsigned int)u) << 16; return v.f;
}
__device__ __forceinline__ ush f2bf(float f) {
    union { float ff; unsigned int i; } v; v.ff = f;
    unsigned int x = v.i;
    return (ush)((x + 0x7FFFu + ((x >> 16) & 1u)) >> 16);
}
__device__ __forceinline__ void unpack2(unsigned int u, float& f0, float& f1) {
    union { unsigned int i; float f; } a, b;
    a.i = u << 16; b.i = u & 0xFFFF0000u;
    f0 = a.f; f1 = b.f;
}

// ---------------- Kernel P: the 5 projections ----------------
// grid (1024 row-tiles, 5 matrices), block 256.
// m=0: Q=EW@WQ^T (->QU[:,0:128], *scale)   m=1: K (->KU[:,0:128], *scale)
// m=2: UQ=ES@UQ^T (->QU[:,128:256])        m=3: UK (->KU[:,128:256])
// m=4: V=EW@V^T (->Vp fp32, no scale)
__global__ __launch_bounds__(256) void proj_kernel(
    const float* __restrict__ EW, const float* __restrict__ ES,
    const float* __restrict__ W0, const float* __restrict__ b0,
    const float* __restrict__ W1, const float* __restrict__ b1,
    const float* __restrict__ W2, const float* __restrict__ b2,
    const float* __restrict__ W3, const float* __restrict__ b3,
    const float* __restrict__ W4, const float* __restrict__ b4,
    ush* __restrict__ QU, ush* __restrict__ KU, float* __restrict__ Vp)
{
    __shared__ float Xt[32][128];
    __shared__ float Wt[64][132];   // W transposed, pitch 132 (16B aligned, conflict-free)

    const int m = blockIdx.y;
    const int rowBase = blockIdx.x * 32;
    const int tid = threadIdx.x;

    const float* X  = (m == 2 || m == 3) ? ES : EW;
    const float* W  = (m == 0) ? W0 : (m == 1) ? W1 : (m == 2) ? W2 : (m == 3) ? W3 : W4;
    const float* Bv = (m == 0) ? b0 : (m == 1) ? b1 : (m == 2) ? b2 : (m == 3) ? b3 : b4;
    const float scl = (m == 4) ? 1.0f : 0.044194173824159216f;  // 1/(2*sqrt(128))

    // stage X rows [32][128]
    #pragma unroll
    for (int it = 0; it < 4; ++it) {
        int linear = it * 1024 + tid * 4;
        int r = linear >> 7, d = linear & 127;
        float4 v = *(const float4*)(X + (size_t)(rowBase + r) * ND + d);
        *(float4*)(&Xt[r][d]) = v;
    }

    const int jg = tid & 31;   // cols jg*4..+3
    const int rg = tid >> 5;   // rows rg*4..+3

    float acc[4][4] = {};

    for (int dt = 0; dt < 128; dt += 64) {
        __syncthreads();
        // stage W[j][dt..dt+63] transposed -> Wt[d][j]
        #pragma unroll
        for (int it = 0; it < 8; ++it) {
            int linear = it * 1024 + tid * 4;
            int j = linear >> 6, d = linear & 63;
            float4 v = *(const float4*)(W + (size_t)j * ND + dt + d);
            Wt[d + 0][j] = v.x; Wt[d + 1][j] = v.y; Wt[d + 2][j] = v.z; Wt[d + 3][j] = v.w;
        }
        __syncthreads();
        #pragma unroll 4
        for (int d = 0; d < 64; d += 4) {
            float x[4][4];
            #pragma unroll
            for (int rr = 0; rr < 4; ++rr) {
                float4 v = *(const float4*)(&Xt[rg * 4 + rr][dt + d]);
                x[rr][0] = v.x; x[rr][1] = v.y; x[rr][2] = v.z; x[rr][3] = v.w;
            }
            #pragma unroll
            for (int dd = 0; dd < 4; ++dd) {
                float4 w = *(const float4*)(&Wt[d + dd][jg * 4]);
                float wc[4] = { w.x, w.y, w.z, w.w };
                #pragma unroll
                for (int rr = 0; rr < 4; ++rr)
                    #pragma unroll
                    for (int cc = 0; cc < 4; ++cc)
                        acc[rr][cc] += x[rr][dd] * wc[cc];
            }
        }
    }

    float bias[4];
    #pragma unroll
    for (int cc = 0; cc < 4; ++cc) bias[cc] = Bv[jg * 4 + cc];

    if (m == 4) {
        #pragma unroll
        for (int rr = 0; rr < 4; ++rr) {
            int row = rowBase + rg * 4 + rr;
            float4 o;
            o.x = acc[rr][0] + bias[0];
            o.y = acc[rr][1] + bias[1];
            o.z = acc[rr][2] + bias[2];
            o.w = acc[rr][3] + bias[3];
            *(float4*)(Vp + (size_t)row * ND + jg * 4) = o;
        }
    } else {
        ush* dst = (m == 0 || m == 2) ? QU : KU;
        const int colOff = (m <= 1) ? 0 : 128;
        #pragma unroll
        for (int rr = 0; rr < 4; ++rr) {
            int row = rowBase + rg * 4 + rr;
            ushort4 o;
            o.x = f2bf((acc[rr][0] + bias[0]) * scl);
            o.y = f2bf((acc[rr][1] + bias[1]) * scl);
            o.z = f2bf((acc[rr][2] + bias[2]) * scl);
            o.w = f2bf((acc[rr][3] + bias[3]) * scl);
            *(ushort4*)(dst + (size_t)row * NK + colOff + jg * 4) = o;
        }
    }
}

// ---------------- Kernel D: denom[b][l] = sum_j exp(alpha[b][l][j]) ----------------
// grid (8 row-tiles, 64 batches), block 256. 64 rows/block, all 512 cols.
__global__ __launch_bounds__(256) void denom_kernel(
    const ush* __restrict__ QU, const ush* __restrict__ KU,
    float* __restrict__ denom)
{
    __shared__ float QUf[64][260];  // full-K rows, pitch 260 (16B aligned)
    __shared__ float KUt[64][36];   // per-ktile cols

    const int b = blockIdx.y;
    const int l0 = blockIdx.x * 64;
    const int tid = threadIdx.x;
    const size_t base = (size_t)b * NL * NK;

    // stage QUf: rows l0..l0+63, k 0..255 (bf16 -> f32)
    #pragma unroll
    for (int it = 0; it < 8; ++it) {
        int linear = it * 2048 + tid * 8;
        int r = linear >> 8, k = linear & 255;
        uint4 u = *(const uint4*)(QU + base + (size_t)(l0 + r) * NK + k);
        float f0,f1,f2,f3,f4,f5,f6,f7;
        unpack2(u.x, f0, f1); unpack2(u.y, f2, f3);
        unpack2(u.z, f4, f5); unpack2(u.w, f6, f7);
        QUf[r][k+0]=f0; QUf[r][k+1]=f1; QUf[r][k+2]=f2; QUf[r][k+3]=f3;
        QUf[r][k+4]=f4; QUf[r][k+5]=f5; QUf[r][k+6]=f6; QUf[r][k+7]=f7;
    }

    const int rg = tid >> 4;  // 0..15, rows rg + 16*rr
    const int cg = tid & 15;  // 0..15, cols cg + 16*cc

    float rowsum[4] = {0.f, 0.f, 0.f, 0.f};

    for (int jt = 0; jt < 8; ++jt) {
        const int j0 = jt * 64;
        float acc[4][4] = {};
        for (int kt = 0; kt < 8; ++kt) {
            const int k0 = kt * 32;
            __syncthreads();
            {   // stage KUt: rows j0..j0+63, k k0..k0+31
                int r = tid >> 2;
                int kc = (tid & 3) * 8;
                uint4 u = *(const uint4*)(KU + base + (size_t)(j0 + r) * NK + k0 + kc);
                float f0,f1,f2,f3,f4,f5,f6,f7;
                unpack2(u.x, f0, f1); unpack2(u.y, f2, f3);
                unpack2(u.z, f4, f5); unpack2(u.w, f6, f7);
                KUt[r][kc+0]=f0; KUt[r][kc+1]=f1; KUt[r][kc+2]=f2; KUt[r][kc+3]=f3;
                KUt[r][kc+4]=f4; KUt[r][kc+5]=f5; KUt[r][kc+6]=f6; KUt[r][kc+7]=f7;
            }
            __syncthreads();
            #pragma unroll
            for (int kq = 0; kq < 8; ++kq) {
                const int kk = kq * 4;
                float q[4][4], kv[4][4];
                #pragma unroll
                for (int rr = 0; rr < 4; ++rr) {
                    float4 v = *(const float4*)(&QUf[rg + 16 * rr][k0 + kk]);
                    q[rr][0]=v.x; q[rr][1]=v.y; q[rr][2]=v.z; q[rr][3]=v.w;
                }
                #pragma unroll
                for (int cc = 0; cc < 4; ++cc) {
                    float4 v = *(const float4*)(&KUt[cg + 16 * cc][kk]);
                    kv[cc][0]=v.x; kv[cc][1]=v.y; kv[cc][2]=v.z; kv[cc][3]=v.w;
                }
                #pragma unroll
                for (int rr = 0; rr < 4; ++rr)
                    #pragma unroll
                    for (int cc = 0; cc < 4; ++cc)
                        #pragma unroll
                        for (int dd = 0; dd < 4; ++dd)
                            acc[rr][cc] += q[rr][dd] * kv[cc][dd];
            }
        }
        #pragma unroll
        for (int rr = 0; rr < 4; ++rr)
            #pragma unroll
            for (int cc = 0; cc < 4; ++cc)
                rowsum[rr] += __expf(acc[rr][cc]);
    }

    #pragma unroll
    for (int msk = 1; msk <= 8; msk <<= 1) {
        #pragma unroll
        for (int rr = 0; rr < 4; ++rr)
            rowsum[rr] += __shfl_xor(rowsum[rr], msk, 16);
    }
    if (cg == 0) {
        #pragma unroll
        for (int rr = 0; rr < 4; ++rr)
            denom[b * NL + l0 + rg + 16 * rr] = rowsum[rr];
    }
}

// ---------------- Kernel R: out[b][d][c] = sum_l Vv[d][l]*exp(alpha[l][c])/denom[c] ----------------
// grid (8 col-tiles, 64 batches), block 512.
__global__ __launch_bounds__(512) void result_kernel(
    const ush* __restrict__ QU, const ush* __restrict__ KU,
    const float* __restrict__ Vp, const float* __restrict__ denom,
    float* __restrict__ out)
{
    __shared__ float QUt[64][36];
    __shared__ float KUt[64][36];
    __shared__ float Pl[64][68];    // [c][l]
    __shared__ float Vvt[128][68];  // [d][l]

    const int b = blockIdx.y;
    const int c0 = blockIdx.x * 64;
    const int tid = threadIdx.x;
    const size_t base = (size_t)b * NL * NK;

    const int cg = tid & 15;   // cols c = cg + 16*cc
    const int rg = tid >> 4;   // 0..31; alpha rows rg+32*rr, PV d rows rg+32*dd

    float rdenom[4];
    #pragma unroll
    for (int cc = 0; cc < 4; ++cc)
        rdenom[cc] = 1.0f / denom[b * NL + c0 + cg + 16 * cc];

    float oacc[4][4] = {};  // [dd][cc]

    for (int lt = 0; lt < 8; ++lt) {
        const int l0 = lt * 64;
        // stage Vvt[d][l] = Vp flat [b, d*512 + l0 + l]  (value reinterpreted [D][L])
        #pragma unroll
        for (int it = 0; it < 4; ++it) {
            int linear = it * 2048 + tid * 4;
            int d = linear >> 6, lq = linear & 63;
            float4 v = *(const float4*)(Vp + (size_t)b * (ND * NL) + (size_t)d * NL + l0 + lq);
            *(float4*)(&Vvt[d][lq]) = v;
        }
        float aacc[2][4] = {};
        for (int kt = 0; kt < 8; ++kt) {
            const int k0 = kt * 32;
            __syncthreads();
            {   // stage QUt (rows l0..) and KUt (rows c0..), k0..k0+31
                int r = tid >> 3;
                int kc = (tid & 7) * 4;
                ushort4 uq = *(const ushort4*)(QU + base + (size_t)(l0 + r) * NK + k0 + kc);
                QUt[r][kc+0]=bf2f(uq.x); QUt[r][kc+1]=bf2f(uq.y);
                QUt[r][kc+2]=bf2f(uq.z); QUt[r][kc+3]=bf2f(uq.w);
                ushort4 uk = *(const ushort4*)(KU + base + (size_t)(c0 + r) * NK + k0 + kc);
                KUt[r][kc+0]=bf2f(uk.x); KUt[r][kc+1]=bf2f(uk.y);
                KUt[r][kc+2]=bf2f(uk.z); KUt[r][kc+3]=bf2f(uk.w);
            }
            __syncthreads();
            #pragma unroll
            for (int kq = 0; kq < 8; ++kq) {
                const int kk = kq * 4;
                float q[2][4], kv[4][4];
                #pragma unroll
                for (int rr = 0; rr < 2; ++rr) {
                    float4 v = *(const float4*)(&QUt[rg + 32 * rr][kk]);
                    q[rr][0]=v.x; q[rr][1]=v.y; q[rr][2]=v.z; q[rr][3]=v.w;
                }
                #pragma unroll
                for (int cc = 0; cc < 4; ++cc) {
                    float4 v = *(const float4*)(&KUt[cg + 16 * cc][kk]);
                    kv[cc][0]=v.x; kv[cc][1]=v.y; kv[cc][2]=v.z; kv[cc][3]=v.w;
                }
                #pragma unroll
                for (int rr = 0; rr < 2; ++rr)
                    #pragma unroll
                    for (int cc = 0; cc < 4; ++cc)
                        #pragma unroll
                        for (int dd = 0; dd < 4; ++dd)
                            aacc[rr][cc] += q[rr][dd] * kv[cc][dd];
            }
        }
        // exp, divide by denom(col), store P transposed: Pl[c][l]
        #pragma unroll
        for (int rr = 0; rr < 2; ++rr)
            #pragma unroll
            for (int cc = 0; cc < 4; ++cc)
                Pl[cg + 16 * cc][rg + 32 * rr] = __expf(aacc[rr][cc]) * rdenom[cc];
        __syncthreads();
        // PV: oacc[dd][cc] += sum_l Vvt[rg+32dd][l] * Pl[cg+16cc][l]
        #pragma unroll
        for (int lq = 0; lq < 16; ++lq) {
            const int l = lq * 4;
            float vv[4][4], pp[4][4];
            #pragma unroll
            for (int dd = 0; dd < 4; ++dd) {
                float4 v = *(const float4*)(&Vvt[rg + 32 * dd][l]);
                vv[dd][0]=v.x; vv[dd][1]=v.y; vv[dd][2]=v.z; vv[dd][3]=v.w;
            }
            #pragma unroll
            for (int cc = 0; cc < 4; ++cc) {
                float4 v = *(const float4*)(&Pl[cg + 16 * cc][l]);
                pp[cc][0]=v.x; pp[cc][1]=v.y; pp[cc][2]=v.z; pp[cc][3]=v.w;
            }
            #pragma unroll
            for (int dd = 0; dd < 4; ++dd)
                #pragma unroll
                for (int cc = 0; cc < 4; ++cc)
                    #pragma unroll
                    for (int i = 0; i < 4; ++i)
                        oacc[dd][cc] += vv[dd][i] * pp[cc][i];
        }
        __syncthreads();
    }
    // out flat == result flat: out[b*D*L + d*L + c]
    #pragma unroll
    for (int dd = 0; dd < 4; ++dd)
        #pragma unroll
        for (int cc = 0; cc < 4; ++cc)
            out[(size_t)b * (ND * NL) + (size_t)(rg + 32 * dd) * NL + c0 + cg + 16 * cc] = oacc[dd][cc];
}

extern "C" void kernel_launch(void* const* d_in, const int* in_sizes, int n_in,
                              void* d_out, int out_size, void* d_ws, size_t ws_size,
                              hipStream_t stream)
{
    const float* EW   = (const float*)d_in[0];
    const float* ES   = (const float*)d_in[1];
    const float* WQ_w = (const float*)d_in[2];
    const float* WQ_b = (const float*)d_in[3];
    const float* WK_w = (const float*)d_in[4];
    const float* WK_b = (const float*)d_in[5];
    const float* UQ_w = (const float*)d_in[6];
    const float* UQ_b = (const float*)d_in[7];
    const float* UK_w = (const float*)d_in[8];
    const float* UK_b = (const float*)d_in[9];
    const float* V_w  = (const float*)d_in[10];
    const float* V_b  = (const float*)d_in[11];

    // ws layout: QU bf16 16MB | KU bf16 16MB | Vp f32 16MB | denom f32 128KB
    if (ws_size < (size_t)48 * 1024 * 1024 + (size_t)NB * NL * sizeof(float)) return;

    char* ws = (char*)d_ws;
    ush*   QU    = (ush*)ws;
    ush*   KU    = (ush*)(ws + (size_t)16 * 1024 * 1024);
    float* Vp    = (float*)(ws + (size_t)32 * 1024 * 1024);
    float* denom = (float*)(ws + (size_t)48 * 1024 * 1024);
    float* outp  = (float*)d_out;

    proj_kernel<<<dim3(1024, 5), 256, 0, stream>>>(EW, ES, WQ_w, WQ_b, WK_w, WK_b,
                                                   UQ_w, UQ_b, UK_w, UK_b, V_w, V_b,
                                                   QU, KU, Vp);
    denom_kernel<<<dim3(8, 64), 256, 0, stream>>>(QU, KU, denom);
    result_kernel<<<dim3(8, 64), 512, 0, stream>>>(QU, KU, Vp, denom, outp);
}

// Round 2
// 111.560 us; speedup vs baseline: 5.4988x; 5.4988x over previous
//
#include <hip/hip_runtime.h>
#include <hip/hip_bf16.h>

#define NB 64
#define NL 512
#define ND 128
#define NK 256   // concat(Q,UQ) contraction dim

typedef unsigned short ush;
typedef __attribute__((ext_vector_type(8))) short short8;
typedef __attribute__((ext_vector_type(16))) float f32x16;

__device__ __forceinline__ ush f2bs(float f) {
    union { __hip_bfloat16 h; ush u; } cv;
    cv.h = __float2bfloat16(f);
    return cv.u;
}
__device__ __forceinline__ short8 pack_bf8(float4 a, float4 b) {
    short8 r;
    r[0] = (short)f2bs(a.x); r[1] = (short)f2bs(a.y);
    r[2] = (short)f2bs(a.z); r[3] = (short)f2bs(a.w);
    r[4] = (short)f2bs(b.x); r[5] = (short)f2bs(b.y);
    r[6] = (short)f2bs(b.z); r[7] = (short)f2bs(b.w);
    return r;
}
__device__ __forceinline__ f32x16 zero16() {
    f32x16 z = {0.f,0.f,0.f,0.f,0.f,0.f,0.f,0.f,0.f,0.f,0.f,0.f,0.f,0.f,0.f,0.f};
    return z;
}

// ---------------- Kernel P: 5 projections via MFMA ----------------
// grid (256 row-tiles of 128, 5 matrices), block 256 (4 waves).
// m=0: Q -> QU[:,0:128]*scale  m=1: K -> KU[:,0:128]*scale
// m=2: UQ -> QU[:,128:256]*sc  m=3: UK -> KU[:,128:256]*sc  m=4: V -> Vb bf16
__global__ __launch_bounds__(256) void proj_kernel(
    const float* __restrict__ EW, const float* __restrict__ ES,
    const float* __restrict__ W0, const float* __restrict__ b0,
    const float* __restrict__ W1, const float* __restrict__ b1,
    const float* __restrict__ W2, const float* __restrict__ b2,
    const float* __restrict__ W3, const float* __restrict__ b3,
    const float* __restrict__ W4, const float* __restrict__ b4,
    ush* __restrict__ QU, ush* __restrict__ KU, ush* __restrict__ Vb)
{
    __shared__ ush Ws[128 * 136];   // W as bf16, pitch 136
    const int m = blockIdx.y;
    const int mt = blockIdx.x;
    const int tid = threadIdx.x;
    const int w = tid >> 6, lane = tid & 63;
    const int l5 = lane & 31, hi = lane >> 5;

    const float* X  = (m == 2 || m == 3) ? ES : EW;
    const float* W  = (m == 0) ? W0 : (m == 1) ? W1 : (m == 2) ? W2 : (m == 3) ? W3 : W4;
    const float* Bv = (m == 0) ? b0 : (m == 1) ? b1 : (m == 2) ? b2 : (m == 3) ? b3 : b4;
    const float scl = (m == 4) ? 1.0f : 0.044194173824159216f;  // 1/(2*sqrt(128))

    // stage W (128x128 f32) -> Ws bf16
    #pragma unroll
    for (int it = 0; it < 16; ++it) {
        int ch = it * 256 + tid;            // 4096 chunks of 4 elems
        int r = ch >> 5, kc = (ch & 31) * 4;
        float4 v = *(const float4*)(W + r * 128 + kc);
        ush* p = &Ws[r * 136 + kc];
        p[0] = f2bs(v.x); p[1] = f2bs(v.y); p[2] = f2bs(v.z); p[3] = f2bs(v.w);
    }
    __syncthreads();

    const int rtile = (w & 1) * 64;   // wave's row range: rtile + {0,32}
    const int ctile = (w >> 1) * 64;  // wave's col range: ctile + {0,32}

    f32x16 acc[2][2];
    acc[0][0] = zero16(); acc[0][1] = zero16();
    acc[1][0] = zero16(); acc[1][1] = zero16();

    const float* xr0 = X + (size_t)(mt * 128 + rtile + l5) * ND + hi * 8;
    #pragma unroll
    for (int ks = 0; ks < 8; ++ks) {
        short8 a0 = pack_bf8(*(const float4*)(xr0 + ks * 16),
                             *(const float4*)(xr0 + ks * 16 + 4));
        short8 a1 = pack_bf8(*(const float4*)(xr0 + 32 * ND + ks * 16),
                             *(const float4*)(xr0 + 32 * ND + ks * 16 + 4));
        #pragma unroll
        for (int nb = 0; nb < 2; ++nb) {
            short8 bf_ = *(const short8*)(&Ws[(ctile + nb * 32 + l5) * 136 + ks * 16 + hi * 8]);
            acc[0][nb] = __builtin_amdgcn_mfma_f32_32x32x16_bf16(a0, bf_, acc[0][nb], 0, 0, 0);
            acc[1][nb] = __builtin_amdgcn_mfma_f32_32x32x16_bf16(a1, bf_, acc[1][nb], 0, 0, 0);
        }
    }

    ush* dstQK = (m == 0 || m == 2) ? QU : KU;
    const int colOff = (m <= 1) ? 0 : 128;
    #pragma unroll
    for (int nb = 0; nb < 2; ++nb) {
        int n = ctile + nb * 32 + l5;
        float bias = Bv[n];
        #pragma unroll
        for (int ms = 0; ms < 2; ++ms) {
            #pragma unroll
            for (int r = 0; r < 16; ++r) {
                int row = mt * 128 + rtile + ms * 32 + (r & 3) + 8 * (r >> 2) + 4 * hi;
                float v = (acc[ms][nb][r] + bias) * scl;
                if (m == 4) Vb[(size_t)row * ND + n] = f2bs(v);
                else        dstQK[(size_t)row * NK + colOff + n] = f2bs(v);
            }
        }
    }
}

// ---------------- Kernel D: denom[b][l] = sum_c exp(alpha[b][l][c]) ----------------
// grid (8 l-tiles of 64, 64 batches), block 256 (4 waves).
// wave w: l rows (w>>1)*32 .. +31, c half (w&1)*256 .. +255
__global__ __launch_bounds__(256) void denom_kernel(
    const ush* __restrict__ QU, const ush* __restrict__ KU,
    float* __restrict__ denom)
{
    __shared__ float red[4][2][16];
    const int b = blockIdx.y, lt = blockIdx.x;
    const int tid = threadIdx.x;
    const int w = tid >> 6, lane = tid & 63;
    const int l5 = lane & 31, hi = lane >> 5;
    const size_t base = (size_t)b * NL * NK;

    const int lsub = (w >> 1) * 32;
    const int chal = (w & 1) * 256;

    short8 af[16];
    const ush* qr = QU + base + (size_t)(lt * 64 + lsub + l5) * NK + hi * 8;
    #pragma unroll
    for (int ks = 0; ks < 16; ++ks) af[ks] = *(const short8*)(qr + ks * 16);

    float rs[16];
    #pragma unroll
    for (int r = 0; r < 16; ++r) rs[r] = 0.f;

    for (int ci = 0; ci < 8; ++ci) {
        const ush* kr = KU + base + (size_t)(chal + ci * 32 + l5) * NK + hi * 8;
        f32x16 acc = zero16();
        #pragma unroll
        for (int ks = 0; ks < 16; ++ks) {
            short8 bf_ = *(const short8*)(kr + ks * 16);
            acc = __builtin_amdgcn_mfma_f32_32x32x16_bf16(af[ks], bf_, acc, 0, 0, 0);
        }
        #pragma unroll
        for (int r = 0; r < 16; ++r) rs[r] += __expf(acc[r]);
    }
    // reduce across the 32 c-lanes (width 32 keeps hi-halves separate)
    #pragma unroll
    for (int mk = 1; mk <= 16; mk <<= 1)
        #pragma unroll
        for (int r = 0; r < 16; ++r)
            rs[r] += __shfl_xor(rs[r], mk, 32);
    if (l5 == 0)
        #pragma unroll
        for (int r = 0; r < 16; ++r) red[w][hi][r] = rs[r];
    __syncthreads();
    if (tid < 64) {
        int r = tid & 15, hi2 = (tid >> 4) & 1, wp = tid >> 5;   // wp 0..1
        float s = red[wp * 2][hi2][r] + red[wp * 2 + 1][hi2][r];
        int l = lt * 64 + wp * 32 + (r & 3) + 8 * (r >> 2) + 4 * hi2;
        denom[b * NL + l] = s;
    }
}

// ---------------- Kernel R: out[b][d][c] = sum_l Vv[d][l] * exp(alpha[l][c]) / denom[c] ----------------
// grid (8 c-tiles of 64, 64 batches), block 256 (4 waves).
// wave w: alpha tile rows lsub=(w>>1)*32, cols csub=(w&1)*32; PV d rows lsub + {0,64}
__global__ __launch_bounds__(256) void result_kernel(
    const ush* __restrict__ QU, const ush* __restrict__ KU,
    const ush* __restrict__ Vb, const float* __restrict__ denom,
    float* __restrict__ out)
{
    __shared__ ush Pt[64 * 72];    // [c][l] bf16, pitch 72
    __shared__ ush Vt[128 * 72];   // [d][l] bf16, pitch 72
    const int b = blockIdx.y, ct = blockIdx.x;
    const int c0 = ct * 64;
    const int tid = threadIdx.x;
    const int w = tid >> 6, lane = tid & 63;
    const int l5 = lane & 31, hi = lane >> 5;
    const size_t base  = (size_t)b * NL * NK;
    const size_t vbase = (size_t)b * (ND * NL);

    const int csub = (w & 1) * 32;
    const int lsub = (w >> 1) * 32;

    // preload this wave's KU c-half fragments for the whole kernel (64 VGPR)
    short8 kf[16];
    const ush* kr = KU + base + (size_t)(c0 + csub + l5) * NK + hi * 8;
    #pragma unroll
    for (int ks = 0; ks < 16; ++ks) kf[ks] = *(const short8*)(kr + ks * 16);

    const float rden = 1.0f / denom[b * NL + c0 + csub + l5];

    f32x16 oacc[2];
    oacc[0] = zero16(); oacc[1] = zero16();

    for (int lt = 0; lt < 8; ++lt) {
        const int l0 = lt * 64;
        if (lt) __syncthreads();   // protect Vt/Pt overwrite vs previous PV reads
        // stage Vt[d][l] from Vb (flat [b][d][l] reinterpret of value)
        #pragma unroll
        for (int it = 0; it < 4; ++it) {
            int ch = it * 256 + tid;        // 1024 chunks of 8 elems
            int d = ch >> 3, lc = (ch & 7) * 8;
            *(short8*)(&Vt[d * 72 + lc]) =
                *(const short8*)(Vb + vbase + (size_t)d * NL + l0 + lc);
        }
        // alpha tile: rows l0+lsub..+31, cols c0+csub..+31, K=256
        f32x16 aacc = zero16();
        const ush* qr = QU + base + (size_t)(l0 + lsub + l5) * NK + hi * 8;
        #pragma unroll
        for (int ks = 0; ks < 16; ++ks) {
            short8 a_ = *(const short8*)(qr + ks * 16);
            aacc = __builtin_amdgcn_mfma_f32_32x32x16_bf16(a_, kf[ks], aacc, 0, 0, 0);
        }
        // P = exp(alpha) * rden -> Pt[c][l] (4 consecutive l per reg-quad)
        #pragma unroll
        for (int q = 0; q < 4; ++q) {
            ushort4 pv;
            pv.x = f2bs(__expf(aacc[q * 4 + 0]) * rden);
            pv.y = f2bs(__expf(aacc[q * 4 + 1]) * rden);
            pv.z = f2bs(__expf(aacc[q * 4 + 2]) * rden);
            pv.w = f2bs(__expf(aacc[q * 4 + 3]) * rden);
            int lrow = lsub + q * 8 + hi * 4;
            *(ushort4*)(&Pt[(csub + l5) * 72 + lrow]) = pv;
        }
        __syncthreads();
        // PV: oacc[db] over d rows lsub + db*64 + l5, cols csub, K = 64 l
        #pragma unroll
        for (int ks = 0; ks < 4; ++ks) {
            short8 pb = *(const short8*)(&Pt[(csub + l5) * 72 + ks * 16 + hi * 8]);
            #pragma unroll
            for (int db = 0; db < 2; ++db) {
                short8 va = *(const short8*)(&Vt[(lsub + db * 64 + l5) * 72 + ks * 16 + hi * 8]);
                oacc[db] = __builtin_amdgcn_mfma_f32_32x32x16_bf16(va, pb, oacc[db], 0, 0, 0);
            }
        }
    }
    #pragma unroll
    for (int db = 0; db < 2; ++db)
        #pragma unroll
        for (int r = 0; r < 16; ++r) {
            int d = lsub + db * 64 + (r & 3) + 8 * (r >> 2) + 4 * hi;
            out[vbase + (size_t)d * NL + c0 + csub + l5] = oacc[db][r];
        }
}

extern "C" void kernel_launch(void* const* d_in, const int* in_sizes, int n_in,
                              void* d_out, int out_size, void* d_ws, size_t ws_size,
                              hipStream_t stream)
{
    const float* EW   = (const float*)d_in[0];
    const float* ES   = (const float*)d_in[1];
    const float* WQ_w = (const float*)d_in[2];
    const float* WQ_b = (const float*)d_in[3];
    const float* WK_w = (const float*)d_in[4];
    const float* WK_b = (const float*)d_in[5];
    const float* UQ_w = (const float*)d_in[6];
    const float* UQ_b = (const float*)d_in[7];
    const float* UK_w = (const float*)d_in[8];
    const float* UK_b = (const float*)d_in[9];
    const float* V_w  = (const float*)d_in[10];
    const float* V_b  = (const float*)d_in[11];

    // ws layout: QU bf16 16MB | KU bf16 16MB | Vb bf16 8MB | denom f32 128KB
    if (ws_size < (size_t)40 * 1024 * 1024 + (size_t)NB * NL * sizeof(float)) return;

    char* ws = (char*)d_ws;
    ush*   QU    = (ush*)ws;
    ush*   KU    = (ush*)(ws + (size_t)16 * 1024 * 1024);
    ush*   Vb    = (ush*)(ws + (size_t)32 * 1024 * 1024);
    float* denom = (float*)(ws + (size_t)40 * 1024 * 1024);
    float* outp  = (float*)d_out;

    proj_kernel<<<dim3(256, 5), 256, 0, stream>>>(EW, ES, WQ_w, WQ_b, WK_w, WK_b,
                                                  UQ_w, UQ_b, UK_w, UK_b, V_w, V_b,
                                                  QU, KU, Vb);
    denom_kernel<<<dim3(8, 64), 256, 0, stream>>>(QU, KU, denom);
    result_kernel<<<dim3(8, 64), 256, 0, stream>>>(QU, KU, Vb, denom, outp);
}